// Round 1
// baseline (1225.834 us; speedup 1.0000x reference)
//
#include <hip/hip_runtime.h>

#define BHn 32
#define Nn 2048
#define Dn 64
#define KSEL 30

// ---------------- Phase A: scores = q @ k^T (per head) ----------------
// tile: 128 rows x 64 cols, 256 threads, 8x4 microtile, K = 64 staged once.
__global__ __launch_bounds__(256) void score_gemm(
    const float* __restrict__ q, const float* __restrict__ k,
    float* __restrict__ scores) {
  __shared__ float qs[Dn][128];  // [d][row]
  __shared__ float ks[Dn][64];   // [d][col]
  const int t = threadIdx.x;
  const int bh = blockIdx.z;
  const int r0 = blockIdx.y * 128;
  const int c0 = blockIdx.x * 64;
  const float* qb = q + ((size_t)bh * Nn + r0) * Dn;
  const float* kb = k + ((size_t)bh * Nn + c0) * Dn;

#pragma unroll
  for (int m = 0; m < 8; ++m) {  // 128 rows * 16 float4-chunks / 256 threads
    int lin = t + 256 * m;
    int rr = lin >> 4, ch = lin & 15;
    float4 a = *(const float4*)(qb + rr * Dn + ch * 4);
    qs[ch * 4 + 0][rr] = a.x;
    qs[ch * 4 + 1][rr] = a.y;
    qs[ch * 4 + 2][rr] = a.z;
    qs[ch * 4 + 3][rr] = a.w;
  }
#pragma unroll
  for (int m = 0; m < 4; ++m) {  // 64 rows * 16 chunks / 256 threads
    int lin = t + 256 * m;
    int rr = lin >> 4, ch = lin & 15;
    float4 a = *(const float4*)(kb + rr * Dn + ch * 4);
    ks[ch * 4 + 0][rr] = a.x;
    ks[ch * 4 + 1][rr] = a.y;
    ks[ch * 4 + 2][rr] = a.z;
    ks[ch * 4 + 3][rr] = a.w;
  }
  __syncthreads();

  const int i = t >> 4;  // row group: rows 8i..8i+7
  const int j = t & 15;  // col group: cols 4j..4j+3
  float acc[8][4] = {};
#pragma unroll 8
  for (int d = 0; d < Dn; ++d) {
    float4 k4 = *(const float4*)&ks[d][4 * j];
    float4 qa = *(const float4*)&qs[d][8 * i];
    float4 qc = *(const float4*)&qs[d][8 * i + 4];
    float qv[8] = {qa.x, qa.y, qa.z, qa.w, qc.x, qc.y, qc.z, qc.w};
    float kv[4] = {k4.x, k4.y, k4.z, k4.w};
#pragma unroll
    for (int a = 0; a < 8; ++a)
#pragma unroll
      for (int b = 0; b < 4; ++b) acc[a][b] = fmaf(qv[a], kv[b], acc[a][b]);
  }

  float* outp = scores + ((size_t)bh * Nn + (r0 + 8 * i)) * Nn + c0 + 4 * j;
#pragma unroll
  for (int a = 0; a < 8; ++a) {
    float4 vv = make_float4(acc[a][0], acc[a][1], acc[a][2], acc[a][3]);
    *(float4*)(outp + (size_t)a * Nn) = vv;
  }
}

// ------------- Phase B: per-row top-30 select + softmax + AV -------------
// One 256-thread block per (bh, row). Scores read from / attn written to the
// same region (in-place; block owns its row exclusively).
__global__ __launch_bounds__(256) void topk_softmax_av(
    float* __restrict__ attn, const float* __restrict__ v,
    float* __restrict__ ctx) {
  const int t = threadIdx.x;
  const int row = blockIdx.x;
  const int bh = blockIdx.y;
  float* srow = attn + ((size_t)bh * Nn + row) * Nn;

  // load 8 scores/thread, order-preserving uint transform
  float s[8];
  unsigned u[8];
#pragma unroll
  for (int j = 0; j < 8; ++j) {
    s[j] = srow[t + 256 * j];
    unsigned b = __float_as_uint(s[j]);
    u[j] = (b & 0x80000000u) ? ~b : (b | 0x80000000u);
  }

  __shared__ unsigned hist[256];
  __shared__ unsigned suf[256];
  __shared__ int s_bin, s_above, s_bin2, s_above2;

  // ---- level 1: histogram of top 8 bits ----
  hist[t] = 0;
  __syncthreads();
#pragma unroll
  for (int j = 0; j < 8; ++j) atomicAdd(&hist[u[j] >> 24], 1u);
  __syncthreads();
  // suffix scan
  suf[t] = hist[t];
  __syncthreads();
  for (int off = 1; off < 256; off <<= 1) {
    unsigned add = (t + off < 256) ? suf[t + off] : 0u;
    __syncthreads();
    suf[t] += add;
    __syncthreads();
  }
  {
    unsigned above = (t < 255) ? suf[t + 1] : 0u;
    if (suf[t] >= (unsigned)KSEL && above < (unsigned)KSEL) {
      s_bin = t;
      s_above = (int)above;
    }
  }
  __syncthreads();
  const int binA = s_bin;
  const int need1 = KSEL - s_above;  // >=1

  // ---- level 2: histogram of bits 16..23 within binA ----
  hist[t] = 0;
  __syncthreads();
#pragma unroll
  for (int j = 0; j < 8; ++j)
    if ((int)(u[j] >> 24) == binA) atomicAdd(&hist[(u[j] >> 16) & 255u], 1u);
  __syncthreads();
  suf[t] = hist[t];
  __syncthreads();
  for (int off = 1; off < 256; off <<= 1) {
    unsigned add = (t + off < 256) ? suf[t + off] : 0u;
    __syncthreads();
    suf[t] += add;
    __syncthreads();
  }
  {
    unsigned above = (t < 255) ? suf[t + 1] : 0u;
    if (suf[t] >= (unsigned)need1 && above < (unsigned)need1) {
      s_bin2 = t;
      s_above2 = (int)above;
    }
  }
  __syncthreads();
  const unsigned prefix = ((unsigned)binA << 8) | (unsigned)s_bin2;
  const int need2 = need1 - s_above2;  // take this many from the prefix bin

  // ---- exact tie-break among candidates sharing the 16-bit prefix ----
  __shared__ unsigned cu[64];
  __shared__ int cix[64];
  __shared__ int ccnt;
  if (t == 0) ccnt = 0;
  __syncthreads();
#pragma unroll
  for (int j = 0; j < 8; ++j) {
    if ((u[j] >> 16) == prefix) {
      int p = atomicAdd(&ccnt, 1);
      if (p < 64) {
        cu[p] = u[j];
        cix[p] = t + 256 * j;
      }
    }
  }
  __syncthreads();
  const int C = min(ccnt, 64);

  // ---- row max ----
  __shared__ float redf[256];
  float lm = -3.0e38f;
#pragma unroll
  for (int j = 0; j < 8; ++j) lm = fmaxf(lm, s[j]);
  redf[t] = lm;
  __syncthreads();
  for (int off = 128; off > 0; off >>= 1) {
    if (t < off) redf[t] = fmaxf(redf[t], redf[t + off]);
    __syncthreads();
  }
  const float m = redf[0];
  __syncthreads();

  // ---- selection flags + exp sum ----
  int selmask = 0;
  float lz = 0.0f;
#pragma unroll
  for (int j = 0; j < 8; ++j) {
    unsigned p16 = u[j] >> 16;
    bool sel = false;
    if (p16 > prefix) {
      sel = true;
    } else if (p16 == prefix) {
      int col = t + 256 * j;
      int r = 0;
      for (int c = 0; c < C; ++c)
        r += (cu[c] > u[j]) || (cu[c] == u[j] && cix[c] < col);
      sel = (r < need2);  // rank within prefix bin (value desc, index asc)
    }
    if (sel) {
      selmask |= 1 << j;
      lz += __expf(s[j] - m);
    }
  }
  redf[t] = lz;
  __syncthreads();
  for (int off = 128; off > 0; off >>= 1) {
    if (t < off) redf[t] += redf[t + off];
    __syncthreads();
  }
  const float invZ = 1.0f / redf[0];
  __syncthreads();

  // ---- write attn row (zeros + weights), build compact (col, w) list ----
  __shared__ int sc[64];
  __shared__ float sw[64];
  __shared__ int scnt;
  if (t == 0) scnt = 0;
  __syncthreads();
#pragma unroll
  for (int j = 0; j < 8; ++j) {
    float w = 0.0f;
    if (selmask & (1 << j)) {
      w = __expf(s[j] - m) * invZ;
      int p = atomicAdd(&scnt, 1);
      if (p < 64) {
        sc[p] = t + 256 * j;
        sw[p] = w;
      }
    }
    srow[t + 256 * j] = w;
  }
  __syncthreads();
  const int M = min(scnt, 64);  // == 30

  // ---- context[row][d] = sum_j w_j * v[col_j][d] ----
  const int d = t & 63, g = t >> 6;
  const float* vb = v + (size_t)bh * Nn * Dn;
  float acc = 0.0f;
  for (int p = g; p < M; p += 4) acc += sw[p] * vb[(size_t)sc[p] * Dn + d];
  redf[t] = acc;
  __syncthreads();
  if (t < 64) {
    ctx[((size_t)bh * Nn + row) * Dn + t] =
        redf[t] + redf[t + 64] + redf[t + 128] + redf[t + 192];
  }
}

extern "C" void kernel_launch(void* const* d_in, const int* in_sizes, int n_in,
                              void* d_out, int out_size, void* d_ws,
                              size_t ws_size, hipStream_t stream) {
  const float* q = (const float*)d_in[0];
  const float* k = (const float*)d_in[1];
  const float* v = (const float*)d_in[2];
  float* out = (float*)d_out;
  float* ctx = out;                                // [32,2048,64]
  float* attn = out + (size_t)BHn * Nn * Dn;       // [32,2048,2048]

  dim3 gA(Nn / 64, Nn / 128, BHn);  // (32,16,32)
  score_gemm<<<gA, 256, 0, stream>>>(q, k, attn);

  dim3 gB(Nn, BHn);  // one block per row
  topk_softmax_av<<<gB, 256, 0, stream>>>(attn, v, ctx);
}

// Round 2
// 1202.278 us; speedup vs baseline: 1.0196x; 1.0196x over previous
//
#include <hip/hip_runtime.h>

#define BHn 32
#define Nn 2048
#define Dn 64
#define KSEL 30
#define CAP 256

typedef short bf16x8 __attribute__((ext_vector_type(8)));
typedef float f32x4 __attribute__((ext_vector_type(4)));

__device__ __forceinline__ ushort bf16_rne(float x) {
  unsigned u = __float_as_uint(x);
  return (ushort)((u + 0x7fffu + ((u >> 16) & 1u)) >> 16);
}
// order-preserving float->uint
__device__ __forceinline__ unsigned ford(float x) {
  unsigned b = __float_as_uint(x);
  return (b & 0x80000000u) ? ~b : (b | 0x80000000u);
}

// ============ K1: scores = q @ k^T via split-bf16 MFMA, 128x128 tile ============
__global__ __launch_bounds__(256, 2) void score_gemm_mfma(
    const float* __restrict__ q, const float* __restrict__ k,
    float* __restrict__ scores) {
  // XOR-swizzled (16B-chunk ^ row&7) to kill fragment-read bank conflicts.
  __shared__ ushort qh[128][64], ql[128][64], kh[128][64], kl[128][64];  // 64 KB
  const int t = threadIdx.x;
  const int bh = blockIdx.z;
  const int r0 = blockIdx.y * 128, c0 = blockIdx.x * 128;
  const float* qb = q + ((size_t)bh * Nn + r0) * Dn;
  const float* kb = k + ((size_t)bh * Nn + c0) * Dn;

#pragma unroll
  for (int i = 0; i < 8; ++i) {  // q tile: 128 rows x 16 float4
    int c = t + 256 * i;
    int row = c >> 4, f4 = c & 15;
    float4 a = *(const float4*)(qb + row * Dn + f4 * 4);
    int sp = (((f4 >> 1) ^ (row & 7)) << 1) | (f4 & 1);
    ushort4 hi, lo;
    hi.x = bf16_rne(a.x); lo.x = bf16_rne(a.x - __uint_as_float((unsigned)hi.x << 16));
    hi.y = bf16_rne(a.y); lo.y = bf16_rne(a.y - __uint_as_float((unsigned)hi.y << 16));
    hi.z = bf16_rne(a.z); lo.z = bf16_rne(a.z - __uint_as_float((unsigned)hi.z << 16));
    hi.w = bf16_rne(a.w); lo.w = bf16_rne(a.w - __uint_as_float((unsigned)hi.w << 16));
    *(ushort4*)&qh[row][sp * 4] = hi;
    *(ushort4*)&ql[row][sp * 4] = lo;
  }
#pragma unroll
  for (int i = 0; i < 8; ++i) {  // k tile: 128 rows x 16 float4
    int c = t + 256 * i;
    int row = c >> 4, f4 = c & 15;
    float4 a = *(const float4*)(kb + row * Dn + f4 * 4);
    int sp = (((f4 >> 1) ^ (row & 7)) << 1) | (f4 & 1);
    ushort4 hi, lo;
    hi.x = bf16_rne(a.x); lo.x = bf16_rne(a.x - __uint_as_float((unsigned)hi.x << 16));
    hi.y = bf16_rne(a.y); lo.y = bf16_rne(a.y - __uint_as_float((unsigned)hi.y << 16));
    hi.z = bf16_rne(a.z); lo.z = bf16_rne(a.z - __uint_as_float((unsigned)hi.z << 16));
    hi.w = bf16_rne(a.w); lo.w = bf16_rne(a.w - __uint_as_float((unsigned)hi.w << 16));
    *(ushort4*)&kh[row][sp * 4] = hi;
    *(ushort4*)&kl[row][sp * 4] = lo;
  }
  __syncthreads();

  const int lane = t & 63, w = t >> 6;
  const int wr = w >> 1, wc = w & 1;        // wave -> 64x64 quadrant
  const int m = lane & 15, quad = lane >> 4;

  f32x4 acc[4][4];
#pragma unroll
  for (int mt = 0; mt < 4; ++mt)
#pragma unroll
    for (int nt = 0; nt < 4; ++nt) acc[mt][nt] = (f32x4){0.f, 0.f, 0.f, 0.f};

#pragma unroll
  for (int ks = 0; ks < 2; ++ks) {
    bf16x8 aH[4], aL[4], bH[4], bL[4];
#pragma unroll
    for (int mt = 0; mt < 4; ++mt) {
      int r = wr * 64 + mt * 16 + m;
      int ch = (ks * 4 + quad) ^ (r & 7);
      aH[mt] = *(const bf16x8*)&qh[r][ch * 8];
      aL[mt] = *(const bf16x8*)&ql[r][ch * 8];
    }
#pragma unroll
    for (int nt = 0; nt < 4; ++nt) {
      int r = wc * 64 + nt * 16 + m;
      int ch = (ks * 4 + quad) ^ (r & 7);
      bH[nt] = *(const bf16x8*)&kh[r][ch * 8];
      bL[nt] = *(const bf16x8*)&kl[r][ch * 8];
    }
#pragma unroll
    for (int mt = 0; mt < 4; ++mt)
#pragma unroll
      for (int nt = 0; nt < 4; ++nt) {
        acc[mt][nt] = __builtin_amdgcn_mfma_f32_16x16x32_bf16(aL[mt], bH[nt], acc[mt][nt], 0, 0, 0);
        acc[mt][nt] = __builtin_amdgcn_mfma_f32_16x16x32_bf16(aH[mt], bL[nt], acc[mt][nt], 0, 0, 0);
        acc[mt][nt] = __builtin_amdgcn_mfma_f32_16x16x32_bf16(aH[mt], bH[nt], acc[mt][nt], 0, 0, 0);
      }
  }

  // C/D layout: col = lane&15, row = quad*4 + reg
#pragma unroll
  for (int mt = 0; mt < 4; ++mt)
#pragma unroll
    for (int nt = 0; nt < 4; ++nt) {
      size_t base = ((size_t)bh * Nn + (r0 + wr * 64 + mt * 16 + quad * 4)) * Nn +
                    (c0 + wc * 64 + nt * 16 + m);
#pragma unroll
      for (int rg = 0; rg < 4; ++rg) scores[base + (size_t)rg * Nn] = acc[mt][nt][rg];
    }
}

// ============ K2: wave-per-row exact top-30 + softmax + AV (no barriers) ============
__global__ __launch_bounds__(256) void topk_av(
    float* __restrict__ attn, const float* __restrict__ v,
    float* __restrict__ ctx) {
  __shared__ float2 cand[4][CAP];   // (score, col-as-float)
  __shared__ unsigned ccnt[4];
  __shared__ unsigned cutU[4];
  __shared__ int cutC[4];
  __shared__ int sc[4][KSEL];
  __shared__ float sw[4][KSEL];

  const int lane = threadIdx.x & 63, wv = threadIdx.x >> 6;
  const int gw = blockIdx.x * 4 + wv;
  const int row = gw & (Nn - 1), bh = gw >> 11;
  float* srow = attn + ((size_t)bh * Nn + row) * Nn;

  float4 s4[8];
#pragma unroll
  for (int j = 0; j < 8; ++j) s4[j] = *(const float4*)(srow + j * 256 + lane * 4);

  // row max + sum of squares (wave shuffles)
  float mx = -3.4e38f, ss = 0.f;
#pragma unroll
  for (int j = 0; j < 8; ++j) {
    mx = fmaxf(mx, fmaxf(fmaxf(s4[j].x, s4[j].y), fmaxf(s4[j].z, s4[j].w)));
    ss = fmaf(s4[j].x, s4[j].x, ss);
    ss = fmaf(s4[j].y, s4[j].y, ss);
    ss = fmaf(s4[j].z, s4[j].z, ss);
    ss = fmaf(s4[j].w, s4[j].w, ss);
  }
#pragma unroll
  for (int off = 32; off; off >>= 1) {
    mx = fmaxf(mx, __shfl_xor(mx, off));
    ss += __shfl_xor(ss, off);
  }
  const float m = mx;

  // threshold: T0 = 2.41*sigma (E[count] ~ 82); exact uint bisection fallback
  unsigned ulo = 0u, uhi = ford(m);
  unsigned um = ford(2.41f * sqrtf(ss * (1.0f / 2048.0f)));
  if (um >= uhi) um = uhi - 1u;

  auto count = [&](unsigned T) {
    int cc = 0;
#pragma unroll
    for (int j = 0; j < 8; ++j) {
      cc += ford(s4[j].x) > T;
      cc += ford(s4[j].y) > T;
      cc += ford(s4[j].z) > T;
      cc += ford(s4[j].w) > T;
    }
#pragma unroll
    for (int off = 32; off; off >>= 1) cc += __shfl_xor(cc, off);
    return cc;
  };

  int c = count(um);
  for (int it = 0; it < 40 && (c < KSEL || c > 192); ++it) {
    if (c < KSEL) uhi = um; else ulo = um;
    unsigned nm = ulo + ((uhi - ulo) >> 1);
    if (nm == ulo) { um = ulo; c = count(um); break; }
    um = nm;
    c = count(um);
  }

  // append candidates (> um) to LDS list
  if (lane == 0) ccnt[wv] = 0u;
#pragma unroll
  for (int j = 0; j < 8; ++j) {
    float vals[4] = {s4[j].x, s4[j].y, s4[j].z, s4[j].w};
#pragma unroll
    for (int e = 0; e < 4; ++e) {
      if (ford(vals[e]) > um) {
        unsigned pos = atomicAdd(&ccnt[wv], 1u);
        if (pos < CAP) cand[wv][pos] = make_float2(vals[e], __int_as_float(j * 256 + lane * 4 + e));
      }
    }
  }
  const int C = min((int)ccnt[wv], CAP);

  // exact rank among candidates (value desc, index asc); lane handles p, p+64, ...
  unsigned myU[4];
  int myCol[4], rk[4];
  float myS[4];
#pragma unroll
  for (int tt = 0; tt < 4; ++tt) {
    int p = lane + 64 * tt;
    if (p < C) {
      float2 cd = cand[wv][p];
      myS[tt] = cd.x;
      myU[tt] = ford(cd.x);
      myCol[tt] = __float_as_int(cd.y);
    } else {
      myS[tt] = 0.f; myU[tt] = 0u; myCol[tt] = 1 << 30;
    }
    rk[tt] = 0;
  }
  for (int jj = 0; jj < C; ++jj) {
    float2 cd = cand[wv][jj];  // broadcast LDS read
    unsigned uj = ford(cd.x);
    int cj = __float_as_int(cd.y);
#pragma unroll
    for (int tt = 0; tt < 4; ++tt)
      rk[tt] += (uj > myU[tt]) || (uj == myU[tt] && cj < myCol[tt]);
  }

  // 30th element = selection cut
#pragma unroll
  for (int tt = 0; tt < 4; ++tt) {
    int p = lane + 64 * tt;
    if (p < C && rk[tt] == KSEL - 1) { cutU[wv] = myU[tt]; cutC[wv] = myCol[tt]; }
  }
  const unsigned ucut = cutU[wv];
  const int ccut = cutC[wv];

  // Z over selected; compact (col, w) list
  float zl = 0.f, es[4];
#pragma unroll
  for (int tt = 0; tt < 4; ++tt) {
    int p = lane + 64 * tt;
    bool sel = (p < C) && (rk[tt] < KSEL);
    es[tt] = sel ? __expf(myS[tt] - m) : 0.f;
    zl += es[tt];
    if (sel) sc[wv][rk[tt]] = myCol[tt];
  }
#pragma unroll
  for (int off = 32; off; off >>= 1) zl += __shfl_xor(zl, off);
  const float invZ = 1.0f / zl;
#pragma unroll
  for (int tt = 0; tt < 4; ++tt) {
    int p = lane + 64 * tt;
    if (p < C && rk[tt] < KSEL) sw[wv][rk[tt]] = es[tt] * invZ;
  }

  // rewrite attn row: zeros + 30 weights
#pragma unroll
  for (int j = 0; j < 8; ++j) {
    float vals[4] = {s4[j].x, s4[j].y, s4[j].z, s4[j].w};
    float4 o;
    float* po = (float*)&o;
#pragma unroll
    for (int e = 0; e < 4; ++e) {
      unsigned ux = ford(vals[e]);
      int col = j * 256 + lane * 4 + e;
      bool sel = (ux > ucut) || (ux == ucut && col <= ccut);
      po[e] = sel ? __expf(vals[e] - m) * invZ : 0.f;
    }
    *(float4*)(srow + j * 256 + lane * 4) = o;
  }

  // ctx[row][lane] = sum_p w_p * v[col_p][lane]
  const float* vb = v + (size_t)bh * Nn * Dn;
  float acc = 0.f;
#pragma unroll
  for (int p = 0; p < KSEL; ++p)
    acc = fmaf(sw[wv][p], vb[(size_t)sc[wv][p] * Dn + lane], acc);
  ctx[((size_t)bh * Nn + row) * Dn + lane] = acc;
}

extern "C" void kernel_launch(void* const* d_in, const int* in_sizes, int n_in,
                              void* d_out, int out_size, void* d_ws,
                              size_t ws_size, hipStream_t stream) {
  const float* q = (const float*)d_in[0];
  const float* k = (const float*)d_in[1];
  const float* v = (const float*)d_in[2];
  float* out = (float*)d_out;
  float* ctx = out;                           // [32,2048,64]
  float* attn = out + (size_t)BHn * Nn * Dn;  // [32,2048,2048]

  dim3 gA(Nn / 128, Nn / 128, BHn);  // (16,16,32)
  score_gemm_mfma<<<gA, 256, 0, stream>>>(q, k, attn);

  topk_av<<<dim3(BHn * Nn / 4), 256, 0, stream>>>(attn, v, ctx);
}

// Round 3
// 893.703 us; speedup vs baseline: 1.3716x; 1.3453x over previous
//
#include <hip/hip_runtime.h>
#include <hip/hip_bf16.h>

#define BHn 32
#define Nn 2048
#define Dn 64
#define KSEL 30
#define CAP 256

typedef short bf16x8 __attribute__((ext_vector_type(8)));
typedef float f32x4 __attribute__((ext_vector_type(4)));

// order-preserving float->uint
__device__ __forceinline__ unsigned ford(float x) {
  unsigned b = __float_as_uint(x);
  return (b & 0x80000000u) ? ~b : (b | 0x80000000u);
}

// packed split: x = hi(bf16) + lo(bf16), via hw packed cvt
__device__ __forceinline__ void split2(float a, float b, ushort2& hi, ushort2& lo) {
  __hip_bfloat162 h = __float22bfloat162_rn(make_float2(a, b));
  union { __hip_bfloat162 v; ushort2 u; } ch; ch.v = h;
  hi = ch.u;
  float2 hf = __bfloat1622float2(h);
  __hip_bfloat162 l = __float22bfloat162_rn(make_float2(a - hf.x, b - hf.y));
  union { __hip_bfloat162 v; ushort2 u; } cl; cl.v = l;
  lo = cl.u;
}

// ============ K1: scores = q @ k^T via split-bf16 MFMA, 128x128 tile ============
__global__ __launch_bounds__(256, 2) void score_gemm_mfma(
    const float* __restrict__ q, const float* __restrict__ k,
    float* __restrict__ scores) {
  __shared__ ushort qh[128][64], ql[128][64], kh[128][64], kl[128][64];  // 64 KB
  const int t = threadIdx.x;
  const int bh = blockIdx.z;
  const int r0 = blockIdx.y * 128, c0 = blockIdx.x * 128;
  const float* qb = q + ((size_t)bh * Nn + r0) * Dn;
  const float* kb = k + ((size_t)bh * Nn + c0) * Dn;

#pragma unroll
  for (int i = 0; i < 8; ++i) {
    int c = t + 256 * i;
    int row = c >> 4, f4 = c & 15;
    float4 a = *(const float4*)(qb + row * Dn + f4 * 4);
    int sp = (((f4 >> 1) ^ (row & 7)) << 1) | (f4 & 1);
    ushort2 h0, l0, h1, l1;
    split2(a.x, a.y, h0, l0);
    split2(a.z, a.w, h1, l1);
    *(ushort4*)&qh[row][sp * 4] = make_ushort4(h0.x, h0.y, h1.x, h1.y);
    *(ushort4*)&ql[row][sp * 4] = make_ushort4(l0.x, l0.y, l1.x, l1.y);
  }
#pragma unroll
  for (int i = 0; i < 8; ++i) {
    int c = t + 256 * i;
    int row = c >> 4, f4 = c & 15;
    float4 a = *(const float4*)(kb + row * Dn + f4 * 4);
    int sp = (((f4 >> 1) ^ (row & 7)) << 1) | (f4 & 1);
    ushort2 h0, l0, h1, l1;
    split2(a.x, a.y, h0, l0);
    split2(a.z, a.w, h1, l1);
    *(ushort4*)&kh[row][sp * 4] = make_ushort4(h0.x, h0.y, h1.x, h1.y);
    *(ushort4*)&kl[row][sp * 4] = make_ushort4(l0.x, l0.y, l1.x, l1.y);
  }
  __syncthreads();

  const int lane = t & 63, w = t >> 6;
  const int wr = w >> 1, wc = w & 1;
  const int m = lane & 15, quad = lane >> 4;

  f32x4 acc[4][4];
#pragma unroll
  for (int mt = 0; mt < 4; ++mt)
#pragma unroll
    for (int nt = 0; nt < 4; ++nt) acc[mt][nt] = (f32x4){0.f, 0.f, 0.f, 0.f};

#pragma unroll
  for (int ks = 0; ks < 2; ++ks) {
    bf16x8 aH[4], aL[4], bH[4], bL[4];
#pragma unroll
    for (int mt = 0; mt < 4; ++mt) {
      int r = wr * 64 + mt * 16 + m;
      int ch = (ks * 4 + quad) ^ (r & 7);
      aH[mt] = *(const bf16x8*)&qh[r][ch * 8];
      aL[mt] = *(const bf16x8*)&ql[r][ch * 8];
    }
#pragma unroll
    for (int nt = 0; nt < 4; ++nt) {
      int r = wc * 64 + nt * 16 + m;
      int ch = (ks * 4 + quad) ^ (r & 7);
      bH[nt] = *(const bf16x8*)&kh[r][ch * 8];
      bL[nt] = *(const bf16x8*)&kl[r][ch * 8];
    }
#pragma unroll
    for (int mt = 0; mt < 4; ++mt)
#pragma unroll
      for (int nt = 0; nt < 4; ++nt) {
        acc[mt][nt] = __builtin_amdgcn_mfma_f32_16x16x32_bf16(aL[mt], bH[nt], acc[mt][nt], 0, 0, 0);
        acc[mt][nt] = __builtin_amdgcn_mfma_f32_16x16x32_bf16(aH[mt], bL[nt], acc[mt][nt], 0, 0, 0);
        acc[mt][nt] = __builtin_amdgcn_mfma_f32_16x16x32_bf16(aH[mt], bH[nt], acc[mt][nt], 0, 0, 0);
      }
  }

  // C/D layout: col = lane&15, row = quad*4 + reg
#pragma unroll
  for (int mt = 0; mt < 4; ++mt)
#pragma unroll
    for (int nt = 0; nt < 4; ++nt) {
      size_t base = ((size_t)bh * Nn + (r0 + wr * 64 + mt * 16 + quad * 4)) * Nn +
                    (c0 + wc * 64 + nt * 16 + m);
#pragma unroll
      for (int rg = 0; rg < 4; ++rg) scores[base + (size_t)rg * Nn] = acc[mt][nt][rg];
    }
}

// ============ K2: wave-per-row exact top-30 + softmax + AV ============
__global__ __launch_bounds__(256) void topk_av(
    float* __restrict__ attn, const float* __restrict__ v,
    float* __restrict__ ctx) {
  __shared__ float2 cand[4][CAP];
  __shared__ unsigned ccnt[4];
  __shared__ unsigned cutU[4];
  __shared__ int cutC[4];
  __shared__ int sc[4][KSEL];
  __shared__ float sw[4][KSEL];

  const int lane = threadIdx.x & 63, wv = threadIdx.x >> 6;
  const int gw = blockIdx.x * 4 + wv;
  const int row = gw & (Nn - 1), bh = gw >> 11;
  float* srow = attn + ((size_t)bh * Nn + row) * Nn;

  float4 s4[8];
#pragma unroll
  for (int j = 0; j < 8; ++j) s4[j] = *(const float4*)(srow + j * 256 + lane * 4);

  // row max + sum of squares
  float mx = -3.4e38f, ss = 0.f;
#pragma unroll
  for (int j = 0; j < 8; ++j) {
    mx = fmaxf(mx, fmaxf(fmaxf(s4[j].x, s4[j].y), fmaxf(s4[j].z, s4[j].w)));
    ss = fmaf(s4[j].x, s4[j].x, ss);
    ss = fmaf(s4[j].y, s4[j].y, ss);
    ss = fmaf(s4[j].z, s4[j].z, ss);
    ss = fmaf(s4[j].w, s4[j].w, ss);
  }
#pragma unroll
  for (int off = 32; off; off >>= 1) {
    mx = fmaxf(mx, __shfl_xor(mx, off));
    ss += __shfl_xor(ss, off);
  }
  const float m = mx;

  // threshold: z=1.92 -> E[count] ~ 56 (P(count<30) ~ 3e-4: rare bisection)
  unsigned ulo = 0u, uhi = ford(m);
  unsigned um = ford(1.92f * sqrtf(ss * (1.0f / 2048.0f)));
  if (um >= uhi) um = uhi - 1u;

  auto count = [&](unsigned T) {
    int cc = 0;
#pragma unroll
    for (int j = 0; j < 8; ++j) {
      cc += ford(s4[j].x) > T;
      cc += ford(s4[j].y) > T;
      cc += ford(s4[j].z) > T;
      cc += ford(s4[j].w) > T;
    }
#pragma unroll
    for (int off = 32; off; off >>= 1) cc += __shfl_xor(cc, off);
    return cc;
  };

  int c = count(um);
  for (int it = 0; it < 40 && (c < KSEL || c > CAP); ++it) {
    if (c < KSEL) uhi = um; else ulo = um;
    unsigned nm = ulo + ((uhi - ulo) >> 1);
    if (nm == ulo) { um = ulo; c = count(um); break; }
    um = nm;
    c = count(um);
  }

  // append candidates (> um)
  if (lane == 0) ccnt[wv] = 0u;
#pragma unroll
  for (int j = 0; j < 8; ++j) {
    float vals[4] = {s4[j].x, s4[j].y, s4[j].z, s4[j].w};
#pragma unroll
    for (int e = 0; e < 4; ++e) {
      if (ford(vals[e]) > um) {
        unsigned pos = atomicAdd(&ccnt[wv], 1u);
        if (pos < CAP) cand[wv][pos] = make_float2(vals[e], __int_as_float(j * 256 + lane * 4 + e));
      }
    }
  }
  const int C = min((int)ccnt[wv], CAP);
  const int slots = (C + 63) >> 6;

  // exact rank (value desc, index asc); usually slots==1
  float es[4];
  int rk[4], myCol[4];
#pragma unroll 1
  for (int tt = 0; tt < slots; ++tt) {
    int p = lane + 64 * tt;
    unsigned myU = 0u;
    int mc = 1 << 30;
    float msv = 0.f;
    if (p < C) {
      float2 cd = cand[wv][p];
      msv = cd.x;
      myU = ford(cd.x);
      mc = __float_as_int(cd.y);
    }
    int r = 0;
    for (int jj = 0; jj < C; ++jj) {
      float2 cd = cand[wv][jj];
      unsigned uj = ford(cd.x);
      int cj = __float_as_int(cd.y);
      r += (uj > myU) || (uj == myU && cj < mc);
    }
    rk[tt] = r;
    myCol[tt] = mc;
    es[tt] = msv;
    if (p < C && r == KSEL - 1) { cutU[wv] = myU; cutC[wv] = mc; }
  }
  const unsigned ucut = cutU[wv];
  const int ccut = cutC[wv];

  // Z over selected; record cols by rank
  float zl = 0.f;
#pragma unroll 1
  for (int tt = 0; tt < slots; ++tt) {
    int p = lane + 64 * tt;
    bool sel = (p < C) && (rk[tt] < KSEL);
    es[tt] = sel ? __expf(es[tt] - m) : 0.f;
    zl += es[tt];
    if (sel) sc[wv][rk[tt]] = myCol[tt];
  }
#pragma unroll
  for (int off = 32; off; off >>= 1) zl += __shfl_xor(zl, off);
  const float invZ = 1.0f / zl;
#pragma unroll 1
  for (int tt = 0; tt < slots; ++tt) {
    int p = lane + 64 * tt;
    if (p < C && rk[tt] < KSEL) sw[wv][rk[tt]] = es[tt] * invZ;
  }

  // rewrite attn row: zeros + 30 weights (expf only under rare-taken branch)
#pragma unroll
  for (int j = 0; j < 8; ++j) {
    float vals[4] = {s4[j].x, s4[j].y, s4[j].z, s4[j].w};
    float4 o = make_float4(0.f, 0.f, 0.f, 0.f);
    float* po = (float*)&o;
    bool sel[4];
    bool any = false;
#pragma unroll
    for (int e = 0; e < 4; ++e) {
      unsigned ux = ford(vals[e]);
      int col = j * 256 + lane * 4 + e;
      sel[e] = (ux > ucut) || (ux == ucut && col <= ccut);
      any |= sel[e];
    }
    if (__builtin_expect(any, 0)) {
#pragma unroll
      for (int e = 0; e < 4; ++e)
        if (sel[e]) po[e] = __expf(vals[e] - m) * invZ;
    }
    *(float4*)(srow + j * 256 + lane * 4) = o;
  }

  // ctx[row][lane] = sum_p w_p * v[col_p][lane]
  const float* vb = v + (size_t)bh * Nn * Dn;
  float acc = 0.f;
#pragma unroll
  for (int p = 0; p < KSEL; ++p)
    acc = fmaf(sw[wv][p], vb[(size_t)sc[wv][p] * Dn + lane], acc);
  ctx[((size_t)bh * Nn + row) * Dn + lane] = acc;
}

extern "C" void kernel_launch(void* const* d_in, const int* in_sizes, int n_in,
                              void* d_out, int out_size, void* d_ws,
                              size_t ws_size, hipStream_t stream) {
  const float* q = (const float*)d_in[0];
  const float* k = (const float*)d_in[1];
  const float* v = (const float*)d_in[2];
  float* out = (float*)d_out;
  float* ctx = out;                           // [32,2048,64]
  float* attn = out + (size_t)BHn * Nn * Dn;  // [32,2048,2048]

  dim3 gA(Nn / 128, Nn / 128, BHn);  // (16,16,32)
  score_gemm_mfma<<<gA, 256, 0, stream>>>(q, k, attn);

  topk_av<<<dim3(BHn * Nn / 4), 256, 0, stream>>>(attn, v, ctx);
}